// Round 2
// baseline (612.037 us; speedup 1.0000x reference)
//
#include <hip/hip_runtime.h>

// Problem constants (from reference): L=4096 labels, Q=16 slots, B=4096 samples, F=2048 feat
#define L_ 4096
#define Q_ 16
#define B_ 4096
#define F_ 2048
#define NC 16     // number of chunks for hierarchical rank
#define CS 256    // chunk size (NC*CS == B_)

// ws layout (ints):
//   chunkHist : NC*L_   (per-chunk label histograms, written whole — no init pass)
//   winner    : L_      (winning sample index per label, -1 = none)
//   localrank : B_      (rank within chunk)

// Per-chunk: local rank of each sample within its chunk (order-preserving),
// per-chunk label histogram via LDS (no global atomics), and winner[] init.
__global__ void k_rank(const int* __restrict__ labels,
                       int* __restrict__ chunkHist,
                       int* __restrict__ localrank,
                       int* __restrict__ winner) {
    __shared__ int lab[CS];
    __shared__ int hist[L_];
    const int c = blockIdx.x;
    const int t = threadIdx.x;
    const int i = c * CS + t;

    winner[i] = -1;  // NC*CS == L_, each global thread inits one label's winner

    const int myl = labels[i];
    lab[t] = myl;
    #pragma unroll
    for (int k = 0; k < L_ / CS; ++k) hist[k * CS + t] = 0;
    __syncthreads();

    // LDS-broadcast scan: all lanes read the same j -> bank broadcast, no conflict
    int r = 0;
    #pragma unroll 8
    for (int j = 0; j < CS; ++j) {
        r += (j < t && lab[j] == myl) ? 1 : 0;
    }
    localrank[i] = r;
    atomicAdd(&hist[myl], 1);
    __syncthreads();

    // coalesced full-row write; overwrites whatever poison was in ws
    #pragma unroll
    for (int k = 0; k < L_ / CS; ++k)
        chunkHist[c * L_ + k * CS + t] = hist[k * CS + t];
}

// Per sample: reconstruct global rank + total label count, decide if this sample
// is the last writer of slot sample_idx[label]; at most one sample per label matches.
__global__ void k_winner(const int* __restrict__ labels,
                         const int* __restrict__ flags,
                         const int* __restrict__ sidx,
                         const int* __restrict__ chunkHist,
                         const int* __restrict__ localrank,
                         int* __restrict__ winner) {
    const int i = blockIdx.x * blockDim.x + threadIdx.x;
    if (i >= B_) return;
    const int lab = labels[i];
    const int ci = i >> 8;  // i / CS
    int prefix = 0, total = 0;
    #pragma unroll
    for (int c = 0; c < NC; ++c) {
        const int v = chunkHist[c * L_ + lab];
        total += v;
        prefix += (c < ci) ? v : 0;
    }
    const int rank = localrank[i] + prefix;
    const int s = sidx[lab];
    const int fl = flags[lab];
    // (s - fl) mod Q; Q=16 pow2, & works in 2's complement
    const int r0 = (s - fl) & (Q_ - 1);
    if (r0 < total) {
        const int rstar = r0 + Q_ * ((total - 1 - r0) >> 4);  // max rank ≡ r0 (mod Q), < total
        if (rank == rstar) winner[lab] = i;  // unique writer per label
    }
}

// out[l] = winner[l]>=0 ? input_features[winner[l]] : queues[l][sample_idx[l]]
__global__ void k_out(const float* __restrict__ input,
                      const float* __restrict__ queues,
                      const int* __restrict__ sidx,
                      const int* __restrict__ winner,
                      float* __restrict__ out) {
    const int l = blockIdx.x;
    const int w = winner[l];  // wave-uniform branch
    const float4* __restrict__ src =
        (w >= 0) ? (const float4*)(input + (size_t)w * F_)
                 : (const float4*)(queues + ((size_t)l * Q_ + sidx[l]) * F_);
    float4* __restrict__ dst = (float4*)(out + (size_t)l * F_);
    const int t = threadIdx.x;
    // F_/4 = 512 float4 per row; 256 threads x 2
    dst[t]       = src[t];
    dst[t + 256] = src[t + 256];
}

extern "C" void kernel_launch(void* const* d_in, const int* in_sizes, int n_in,
                              void* d_out, int out_size, void* d_ws, size_t ws_size,
                              hipStream_t stream) {
    const float* input  = (const float*)d_in[0];   // [B,F]
    const float* queues = (const float*)d_in[1];   // [L,Q,F]
    const int*   labels = (const int*)d_in[2];     // [B]
    const int*   flags  = (const int*)d_in[3];     // [L]
    const int*   sidx   = (const int*)d_in[4];     // [L]
    float* out = (float*)d_out;                    // [L,F]

    int* chunkHist = (int*)d_ws;           // NC*L_
    int* winner    = chunkHist + NC * L_;  // L_
    int* localrank = winner + L_;          // B_

    k_rank<<<NC, CS, 0, stream>>>(labels, chunkHist, localrank, winner);
    k_winner<<<(B_ + 255) / 256, 256, 0, stream>>>(labels, flags, sidx, chunkHist, localrank, winner);
    k_out<<<L_, 256, 0, stream>>>(input, queues, sidx, winner, out);
}

// Round 3
// 598.067 us; speedup vs baseline: 1.0234x; 1.0234x over previous
//
#include <hip/hip_runtime.h>

// L=4096 labels, Q=16 slots, B=4096 samples, F=2048 features.
// Single fused kernel: block l recomputes the winning sample for its own
// sampled slot from the 16KB labels array (L1-resident broadcast), then
// copies the 8KB output row. No workspace, no inter-kernel deps.
#define L_ 4096
#define Q_ 16
#define B_ 4096
#define F_ 2048

__global__ __launch_bounds__(256) void k_fused(
    const float* __restrict__ input,    // [B,F]
    const float* __restrict__ queues,   // [L,Q,F]
    const int*   __restrict__ labels,   // [B]
    const int*   __restrict__ flags,    // [L]
    const int*   __restrict__ sidx,     // [L]
    float*       __restrict__ out)      // [L,F]
{
    const int l    = blockIdx.x;
    const int t    = threadIdx.x;
    const int lane = t & 63;
    const int wave = t >> 6;

    // --- phase 1: each thread scans 16 contiguous labels [16t, 16t+16) ---
    const int4* lp = (const int4*)(labels + t * 16);
    int4 a = lp[0], b = lp[1], c = lp[2], d = lp[3];
    unsigned mask = 0;
    mask |= (unsigned)(a.x == l) << 0;  mask |= (unsigned)(a.y == l) << 1;
    mask |= (unsigned)(a.z == l) << 2;  mask |= (unsigned)(a.w == l) << 3;
    mask |= (unsigned)(b.x == l) << 4;  mask |= (unsigned)(b.y == l) << 5;
    mask |= (unsigned)(b.z == l) << 6;  mask |= (unsigned)(b.w == l) << 7;
    mask |= (unsigned)(c.x == l) << 8;  mask |= (unsigned)(c.y == l) << 9;
    mask |= (unsigned)(c.z == l) << 10; mask |= (unsigned)(c.w == l) << 11;
    mask |= (unsigned)(d.x == l) << 12; mask |= (unsigned)(d.y == l) << 13;
    mask |= (unsigned)(d.z == l) << 14; mask |= (unsigned)(d.w == l) << 15;
    const int m = __popc(mask);

    // --- phase 2: wave-inclusive scan of m (order = thread order = sample order) ---
    int incl = m;
    #pragma unroll
    for (int off = 1; off < 64; off <<= 1) {
        int v = __shfl_up(incl, off, 64);
        incl += (lane >= off) ? v : 0;
    }

    __shared__ int wtot[4];
    __shared__ int s_win;
    if (lane == 63) wtot[wave] = incl;
    if (t == 0) s_win = -1;
    __syncthreads();

    int woff = 0, total = 0;
    #pragma unroll
    for (int w2 = 0; w2 < 4; ++w2) {
        const int v = wtot[w2];
        total += v;
        woff += (w2 < wave) ? v : 0;
    }
    const int p = woff + incl - m;  // exclusive prefix: matches before index 16t

    const int s  = sidx[l];
    const int r0 = (s - flags[l]) & (Q_ - 1);  // (s - flag) mod 16
    if (r0 < total) {
        // last writer of slot s: max rank ≡ r0 (mod 16), < total
        const int rstar = r0 + (((total - 1 - r0) >> 4) << 4);
        if (rstar >= p && rstar < p + m) {
            int need = rstar - p;          // pick need-th set bit (ascending = index order)
            unsigned mm = mask;
            while (need--) mm &= mm - 1;
            s_win = t * 16 + (__ffs(mm) - 1);
        }
    }
    __syncthreads();

    // --- phase 3: copy the 8KB output row ---
    const int w = s_win;  // block-uniform
    const float4* __restrict__ src =
        (w >= 0) ? (const float4*)(input + (size_t)w * F_)
                 : (const float4*)(queues + ((size_t)l * Q_ + s) * F_);
    float4* __restrict__ dst = (float4*)(out + (size_t)l * F_);
    dst[t]       = src[t];
    dst[t + 256] = src[t + 256];
}

extern "C" void kernel_launch(void* const* d_in, const int* in_sizes, int n_in,
                              void* d_out, int out_size, void* d_ws, size_t ws_size,
                              hipStream_t stream) {
    const float* input  = (const float*)d_in[0];
    const float* queues = (const float*)d_in[1];
    const int*   labels = (const int*)d_in[2];
    const int*   flags  = (const int*)d_in[3];
    const int*   sidx   = (const int*)d_in[4];
    float* out = (float*)d_out;

    k_fused<<<L_, 256, 0, stream>>>(input, queues, labels, flags, sidx, out);
}